// Round 2
// baseline (601.474 us; speedup 1.0000x reference)
//
#include <hip/hip_runtime.h>

// ManifoldConstrainedHyperConnection fused kernel.
// Shapes: x (8192 tokens, 4 streams, 2048 dim) fp32; W_router (24, 2048); b_router (24).
// out (8192, 4, 2048) fp32.
//
// One token per 256-thread block. Each thread owns 8 d-columns of all 4 streams
// (two float4 chunks per stream) in registers -> x read exactly once from HBM.
//
// Round-1 change vs 516us baseline: the 24-row router dot previously ran with
// VGPR=64 (exactly the persistent state: x 32 + s 8 + p 24), so the 48 W_router
// L2 loads serialized one-at-a-time (~300-800cy each) -> ~25-40us block lifetime,
// CU starved, HBM at 38%. Now the loads are issued in 3 groups of 16 with a
// sched_barrier between loads and FMAs, guaranteeing 16 outstanding loads.
// x/out use nontemporal hints (pure streaming, no reuse) to keep W_router hot
// in L2/L3.
//
// Round 2: identical logic (round-1 bench died to a container-acquisition
// failure, not a kernel failure) — resubmitted to get a clean measurement.

#define SINKHORN_ITERS 4
#define EPSV 1e-6f

typedef float f32x4 __attribute__((ext_vector_type(4)));

__global__ __launch_bounds__(256, 4) void mchc_fused(
    const float* __restrict__ x,
    const float* __restrict__ Wr,
    const float* __restrict__ br,
    float* __restrict__ out)
{
    const int token = blockIdx.x;      // 0..8191
    const int tid   = threadIdx.x;     // 0..255
    const int lane  = tid & 63;
    const int wave  = tid >> 6;

    const f32x4* __restrict__ x4 = (const f32x4*)(x + (size_t)token * 8192);
    const f32x4* __restrict__ w4 = (const f32x4*)Wr;
    f32x4*       __restrict__ o4 = (f32x4*)(out + (size_t)token * 8192);

    // ---- load x token slice into registers: xa[w] = chunk tid, xb[w] = chunk tid+256
    // Nontemporal: x is streamed exactly once from HBM; don't let it thrash L2/L3
    // (W_router wants to stay resident there).
    f32x4 xa[4], xb[4];
#pragma unroll
    for (int w = 0; w < 4; ++w) {
        xa[w] = __builtin_nontemporal_load(&x4[w * 512 + tid]);
        xb[w] = __builtin_nontemporal_load(&x4[w * 512 + 256 + tid]);
    }

    // stream-sum (mean * 4; fold the 0.25 into the final logits)
    f32x4 sa = xa[0] + xa[1] + xa[2] + xa[3];
    f32x4 sb = xb[0] + xb[1] + xb[2] + xb[3];

    // ---- 24 router partial dots (W_router is L2-resident).
    // Grouped: issue 16 independent float4 loads, THEN consume. The sched_barrier
    // stops the scheduler from interleaving load->use pairs (which would minimize
    // registers but serialize the L2 latency 48x).
    float p[24];
#pragma unroll
    for (int g = 0; g < 3; ++g) {
        f32x4 wa[8], wb[8];
#pragma unroll
        for (int r = 0; r < 8; ++r) {
            wa[r] = w4[(g * 8 + r) * 512 + tid];
            wb[r] = w4[(g * 8 + r) * 512 + 256 + tid];
        }
        __builtin_amdgcn_sched_barrier(0);
#pragma unroll
        for (int r = 0; r < 8; ++r) {
            f32x4 t = sa * wa[r] + sb * wb[r];
            p[g * 8 + r] = t.x + t.y + t.z + t.w;
        }
    }

    // ---- reduce 24 values across the wave (butterfly), then across 4 waves via LDS
    __shared__ float red[4][24];
    __shared__ float rawbuf[24];
    __shared__ float Mbuf[16];

#pragma unroll
    for (int k = 0; k < 24; ++k) {
        float v = p[k];
        v += __shfl_xor(v, 1);
        v += __shfl_xor(v, 2);
        v += __shfl_xor(v, 4);
        v += __shfl_xor(v, 8);
        v += __shfl_xor(v, 16);
        v += __shfl_xor(v, 32);
        p[k] = v;
    }
    if (lane == 0) {
#pragma unroll
        for (int k = 0; k < 24; ++k) red[wave][k] = p[k];
    }
    __syncthreads();

    if (tid < 24) {
        float r = red[0][tid] + red[1][tid] + red[2][tid] + red[3][tid];
        rawbuf[tid] = 0.25f * r + br[tid];   // mean over W folded in here
    }
    __syncthreads();

    // ---- lanes 0..15 of wave 0: softmaxes + sinkhorn + fold post*pre
    if (tid < 16) {
        const int i = tid >> 2, j = tid & 3;

        float r0 = rawbuf[0], r1 = rawbuf[1], r2 = rawbuf[2], r3 = rawbuf[3];
        float mp = fmaxf(fmaxf(r0, r1), fmaxf(r2, r3));
        float sp = __expf(r0 - mp) + __expf(r1 - mp) + __expf(r2 - mp) + __expf(r3 - mp);
        float pre_j = __expf(rawbuf[j] - mp) / sp;

        float q0 = rawbuf[4], q1 = rawbuf[5], q2 = rawbuf[6], q3 = rawbuf[7];
        float mq = fmaxf(fmaxf(q0, q1), fmaxf(q2, q3));
        float sq = __expf(q0 - mq) + __expf(q1 - mq) + __expf(q2 - mq) + __expf(q3 - mq);
        float post_i = __expf(rawbuf[4 + i] - mq) / sq;

        // residual logits + (-2 off-diag, +2 diag) bias, exponentiate
        float w = __expf(rawbuf[8 + tid] + ((i == j) ? 2.0f : -2.0f));
#pragma unroll
        for (int it = 0; it < SINKHORN_ITERS; ++it) {
            // row normalize: sum over j (lanes differing in bits 0..1)
            float rs = w + __shfl_xor(w, 1);
            rs += __shfl_xor(rs, 2);
            w /= fmaxf(rs, EPSV);
            // col normalize: sum over i (lanes differing in bits 2..3)
            float cs = w + __shfl_xor(w, 4);
            cs += __shfl_xor(cs, 8);
            w /= fmaxf(cs, EPSV);
        }
        Mbuf[tid] = w + post_i * pre_j;   // fold post[i]*pre[j] into the 4x4 mix
    }
    __syncthreads();

    // ---- apply the 4x4 mix to the register-resident x slice
    float M[16];
#pragma unroll
    for (int m = 0; m < 16; ++m) M[m] = Mbuf[m];

#pragma unroll
    for (int i = 0; i < 4; ++i) {
        const float m0 = M[i * 4 + 0], m1 = M[i * 4 + 1];
        const float m2 = M[i * 4 + 2], m3 = M[i * 4 + 3];
        f32x4 oa = m0 * xa[0] + m1 * xa[1] + m2 * xa[2] + m3 * xa[3];
        f32x4 ob = m0 * xb[0] + m1 * xb[1] + m2 * xb[2] + m3 * xb[3];
        __builtin_nontemporal_store(oa, &o4[i * 512 + tid]);
        __builtin_nontemporal_store(ob, &o4[i * 512 + 256 + tid]);
    }
}

extern "C" void kernel_launch(void* const* d_in, const int* in_sizes, int n_in,
                              void* d_out, int out_size, void* d_ws, size_t ws_size,
                              hipStream_t stream) {
    const float* x  = (const float*)d_in[0];
    const float* Wr = (const float*)d_in[1];
    const float* br = (const float*)d_in[2];
    float* out = (float*)d_out;

    const int tokens = in_sizes[0] / (4 * 2048);   // B*T = 8192
    mchc_fused<<<dim3(tokens), dim3(256), 0, stream>>>(x, Wr, br, out);
}

// Round 3
// 515.902 us; speedup vs baseline: 1.1659x; 1.1659x over previous
//
#include <hip/hip_runtime.h>

// ManifoldConstrainedHyperConnection fused kernel.
// Shapes: x (8192 tokens, 4 streams, 2048 dim) fp32; W_router (24, 2048); b_router (24).
// out (8192, 4, 2048) fp32.
//
// One token per 256-thread block.
//
// Round 3: the round-1/2 attempt staged 16 W-loads in registers on TOP of the
// 64 persistent VGPRs (x 32 + sums 8 + p 24) under a 128-VGPR cap -> the
// allocator spilled the staging to scratch (FETCH +110MB, WRITE +221MB,
// 217->285us). Fix: stash the x slice in LDS (32KB/block, thread-private:
// each thread reads back only what it wrote -> no barrier, conflict-free,
// guaranteed hit; 4 blocks x 33KB < 160KB keeps (256,4) occupancy). With x
// out of registers the 8-row W staging groups fit in VGPRs (~105 peak), the
// 16 loads per group genuinely stay in flight, and group 0 is issued with the
// x loads so its L2 latency hides under the x HBM latency. nt hints dropped:
// round-0 FETCH (218MB < 268MB input) showed cross-dispatch L3 residency of x
// that nt loads would forfeit.

#define SINKHORN_ITERS 4
#define EPSV 1e-6f

typedef float f32x4 __attribute__((ext_vector_type(4)));

__global__ __launch_bounds__(256, 4) void mchc_fused(
    const float* __restrict__ x,
    const float* __restrict__ Wr,
    const float* __restrict__ br,
    float* __restrict__ out)
{
    const int token = blockIdx.x;      // 0..8191
    const int tid   = threadIdx.x;     // 0..255
    const int lane  = tid & 63;
    const int wave  = tid >> 6;

    const f32x4* __restrict__ x4 = (const f32x4*)(x + (size_t)token * 8192);
    const f32x4* __restrict__ w4 = (const f32x4*)Wr;
    f32x4*       __restrict__ o4 = (f32x4*)(out + (size_t)token * 8192);

    __shared__ f32x4 xs[8][256];     // 32 KB x stash; xs[c][tid] is thread-private
    __shared__ float red[4][24];
    __shared__ float rawbuf[24];
    __shared__ float Mbuf[16];

    // ---- Phase 1: issue all 8 x loads AND the first 8-row W group together.
    // 24 loads outstanding; consuming x waits only on the older x loads
    // (vmcnt(16)), so W group 0's L2 latency hides under x's HBM latency.
    f32x4 xa[4], xb[4];
#pragma unroll
    for (int w = 0; w < 4; ++w) {
        xa[w] = x4[w * 512 + tid];
        xb[w] = x4[w * 512 + 256 + tid];
    }
    f32x4 wa[8], wb[8];
#pragma unroll
    for (int r = 0; r < 8; ++r) {
        wa[r] = w4[r * 512 + tid];
        wb[r] = w4[r * 512 + 256 + tid];
    }
    __builtin_amdgcn_sched_barrier(0);

    // stream-sum (mean * 4; the 0.25 is folded into the logits later)
    f32x4 sa = xa[0] + xa[1] + xa[2] + xa[3];
    f32x4 sb = xb[0] + xb[1] + xb[2] + xb[3];

    // stash x to LDS; xa/xb registers are dead after this point
#pragma unroll
    for (int w = 0; w < 4; ++w) {
        xs[w][tid]     = xa[w];
        xs[4 + w][tid] = xb[w];
    }
    __builtin_amdgcn_sched_barrier(0);

    // ---- Phase 2: 24 router dots in 3 groups of 8 rows.
    // Peak live regs: sums 8 + staging 64 + p 24 + addressing -> ~105 < 128,
    // so the group structure survives register allocation (no scratch).
    float p[24];
#pragma unroll
    for (int g = 0; g < 3; ++g) {
        if (g > 0) {
#pragma unroll
            for (int r = 0; r < 8; ++r) {
                wa[r] = w4[(g * 8 + r) * 512 + tid];
                wb[r] = w4[(g * 8 + r) * 512 + 256 + tid];
            }
            __builtin_amdgcn_sched_barrier(0);
        }
#pragma unroll
        for (int r = 0; r < 8; ++r) {
            f32x4 t = sa * wa[r] + sb * wb[r];
            p[g * 8 + r] = t.x + t.y + t.z + t.w;
        }
    }

    // ---- Phase 3: reduce 24 values across the wave (butterfly), then across
    // 4 waves via LDS.
#pragma unroll
    for (int k = 0; k < 24; ++k) {
        float v = p[k];
        v += __shfl_xor(v, 1);
        v += __shfl_xor(v, 2);
        v += __shfl_xor(v, 4);
        v += __shfl_xor(v, 8);
        v += __shfl_xor(v, 16);
        v += __shfl_xor(v, 32);
        p[k] = v;
    }
    if (lane == 0) {
#pragma unroll
        for (int k = 0; k < 24; ++k) red[wave][k] = p[k];
    }
    __syncthreads();

    if (tid < 24) {
        float r = red[0][tid] + red[1][tid] + red[2][tid] + red[3][tid];
        rawbuf[tid] = 0.25f * r + br[tid];   // mean over W folded in here
    }
    __syncthreads();

    // ---- Phase 4: lanes 0..15 of wave 0: softmaxes + sinkhorn + fold post*pre
    if (tid < 16) {
        const int i = tid >> 2, j = tid & 3;

        float r0 = rawbuf[0], r1 = rawbuf[1], r2 = rawbuf[2], r3 = rawbuf[3];
        float mp = fmaxf(fmaxf(r0, r1), fmaxf(r2, r3));
        float sp = __expf(r0 - mp) + __expf(r1 - mp) + __expf(r2 - mp) + __expf(r3 - mp);
        float pre_j = __expf(rawbuf[j] - mp) / sp;

        float q0 = rawbuf[4], q1 = rawbuf[5], q2 = rawbuf[6], q3 = rawbuf[7];
        float mq = fmaxf(fmaxf(q0, q1), fmaxf(q2, q3));
        float sq = __expf(q0 - mq) + __expf(q1 - mq) + __expf(q2 - mq) + __expf(q3 - mq);
        float post_i = __expf(rawbuf[4 + i] - mq) / sq;

        // residual logits + (-2 off-diag, +2 diag) bias, exponentiate
        float w = __expf(rawbuf[8 + tid] + ((i == j) ? 2.0f : -2.0f));
#pragma unroll
        for (int it = 0; it < SINKHORN_ITERS; ++it) {
            // row normalize: sum over j (lanes differing in bits 0..1)
            float rs = w + __shfl_xor(w, 1);
            rs += __shfl_xor(rs, 2);
            w /= fmaxf(rs, EPSV);
            // col normalize: sum over i (lanes differing in bits 2..3)
            float cs = w + __shfl_xor(w, 4);
            cs += __shfl_xor(cs, 8);
            w /= fmaxf(cs, EPSV);
        }
        Mbuf[tid] = w + post_i * pre_j;   // fold post[i]*pre[j] into the 4x4 mix
    }
    __syncthreads();

    // ---- Phase 5: read x back from the LDS stash, apply the 4x4 mix, store.
    float M[16];
#pragma unroll
    for (int m = 0; m < 16; ++m) M[m] = Mbuf[m];

    f32x4 ya[4], yb[4];
#pragma unroll
    for (int w = 0; w < 4; ++w) {
        ya[w] = xs[w][tid];
        yb[w] = xs[4 + w][tid];
    }

#pragma unroll
    for (int i = 0; i < 4; ++i) {
        const float m0 = M[i * 4 + 0], m1 = M[i * 4 + 1];
        const float m2 = M[i * 4 + 2], m3 = M[i * 4 + 3];
        f32x4 oa = m0 * ya[0] + m1 * ya[1] + m2 * ya[2] + m3 * ya[3];
        f32x4 ob = m0 * yb[0] + m1 * yb[1] + m2 * yb[2] + m3 * yb[3];
        o4[i * 512 + tid]       = oa;
        o4[i * 512 + 256 + tid] = ob;
    }
}

extern "C" void kernel_launch(void* const* d_in, const int* in_sizes, int n_in,
                              void* d_out, int out_size, void* d_ws, size_t ws_size,
                              hipStream_t stream) {
    const float* x  = (const float*)d_in[0];
    const float* Wr = (const float*)d_in[1];
    const float* br = (const float*)d_in[2];
    float* out = (float*)d_out;

    const int tokens = in_sizes[0] / (4 * 2048);   // B*T = 8192
    mchc_fused<<<dim3(tokens), dim3(256), 0, stream>>>(x, Wr, br, out);
}

// Round 4
// 504.576 us; speedup vs baseline: 1.1920x; 1.0224x over previous
//
#include <hip/hip_runtime.h>

// ManifoldConstrainedHyperConnection fused kernel.
// Shapes: x (8192 tokens, 4 streams, 2048 dim) fp32; W_router (24, 2048); b_router (24).
// out (8192, 4, 2048) fp32.
//
// One token per 256-thread block.
//
// History: baseline 217us/dispatch at VALUBusy 13%, HBM 37%, occ 38% ->
// latency-bound on the 48 dependent W_router loads per thread (~1000cy each
// under 12-wave L2 contention ~= the 50k-cy block lifetime). Rounds 1-3
// tried register-staged load groups; the allocator pinned VGPR=64 twice and
// de-pipelined them (and round-2's nt hints cost +110MB FETCH / +221MB WRITE).
//
// Round 4: compiler-proof pipeline via global_load_lds. W is staged into a
// 16KB LDS buffer in 2-row chunks: 4 fire-and-forget dwordx4 instructions per
// wave (zero dest VGPRs -> nothing for the allocator to serialize), one
// __syncthreads drain per chunk, dot product out of LDS via ds_read_b128.
// 48 serial L2 latencies -> 12 amortized chunk drains. Chunk 0 issues under
// the x HBM latency. x slice stays stashed in LDS (thread-private, no
// barrier needed) so the epilogue re-reads no global memory.
// LDS 48.5KB -> 3 blocks/CU (same residency as baseline).

#define SINKHORN_ITERS 4
#define EPSV 1e-6f

typedef float f32x4 __attribute__((ext_vector_type(4)));

// Direct global->LDS copy, 16B per lane. LDS dest must be wave-uniform;
// HW adds lane*16. Global src is per-lane.
__device__ __forceinline__ void gload_lds16(const float* g, float* l) {
    __builtin_amdgcn_global_load_lds(
        (const __attribute__((address_space(1))) void*)g,
        (__attribute__((address_space(3))) void*)l,
        16, 0, 0);
}

__global__ __launch_bounds__(256, 3) void mchc_fused(
    const float* __restrict__ x,
    const float* __restrict__ Wr,
    const float* __restrict__ br,
    float* __restrict__ out)
{
    const int token = blockIdx.x;      // 0..8191
    const int tid   = threadIdx.x;     // 0..255
    const int lane  = tid & 63;
    const int wave  = tid >> 6;

    const f32x4* __restrict__ x4 = (const f32x4*)(x + (size_t)token * 8192);
    f32x4*       __restrict__ o4 = (f32x4*)(out + (size_t)token * 8192);

    __shared__ float wlds[4096];     // 16KB: one 2-row W chunk (2 x 2048 fp32)
    __shared__ f32x4 xs[8][256];     // 32KB x stash; xs[c][tid] is thread-private
    __shared__ float red[4][24];
    __shared__ float rawbuf[24];
    __shared__ float Mbuf[16];

    // ---- Phase 1: issue x loads, then immediately issue W chunk 0 to LDS.
    // Chunk 0's L2 latency hides entirely under the x HBM wait.
    f32x4 xa[4], xb[4];
#pragma unroll
    for (int w = 0; w < 4; ++w) {
        xa[w] = x4[w * 512 + tid];
        xb[w] = x4[w * 512 + 256 + tid];
    }
    {
        const float* g = Wr + wave * 1024 + lane * 4;   // chunk 0
        float*       l = wlds + wave * 1024;            // wave-uniform
#pragma unroll
        for (int i = 0; i < 4; ++i)
            gload_lds16(g + i * 256, l + i * 256);
    }

    // stream-sum (mean * 4; the 0.25 is folded into the logits later)
    f32x4 sa = xa[0] + xa[1] + xa[2] + xa[3];
    f32x4 sb = xb[0] + xb[1] + xb[2] + xb[3];

    // stash x to LDS; xa/xb registers are dead after this point
#pragma unroll
    for (int w = 0; w < 4; ++w) {
        xs[w][tid]     = xa[w];
        xs[4 + w][tid] = xb[w];
    }

    // ---- Phase 2: 24 router dots, 12 chunks of 2 rows through the LDS buffer.
    float p[24];
#pragma unroll
    for (int c = 0; c < 12; ++c) {
        __syncthreads();   // drains vmcnt -> chunk c resident in wlds
#pragma unroll
        for (int r = 0; r < 2; ++r) {
            f32x4 wa = *(const f32x4*)&wlds[r * 2048 + tid * 4];
            f32x4 wb = *(const f32x4*)&wlds[r * 2048 + 1024 + tid * 4];
            f32x4 t = sa * wa + sb * wb;
            p[c * 2 + r] = t.x + t.y + t.z + t.w;
        }
        __syncthreads();   // all waves done reading before overwrite
        if (c < 11) {
            const float* g = Wr + (c + 1) * 4096 + wave * 1024 + lane * 4;
            float*       l = wlds + wave * 1024;
#pragma unroll
            for (int i = 0; i < 4; ++i)
                gload_lds16(g + i * 256, l + i * 256);
        }
    }

    // ---- Phase 3: reduce 24 values across the wave (butterfly), then across
    // 4 waves via LDS.
#pragma unroll
    for (int k = 0; k < 24; ++k) {
        float v = p[k];
        v += __shfl_xor(v, 1);
        v += __shfl_xor(v, 2);
        v += __shfl_xor(v, 4);
        v += __shfl_xor(v, 8);
        v += __shfl_xor(v, 16);
        v += __shfl_xor(v, 32);
        p[k] = v;
    }
    if (lane == 0) {
#pragma unroll
        for (int k = 0; k < 24; ++k) red[wave][k] = p[k];
    }
    __syncthreads();

    if (tid < 24) {
        float r = red[0][tid] + red[1][tid] + red[2][tid] + red[3][tid];
        rawbuf[tid] = 0.25f * r + br[tid];   // mean over W folded in here
    }
    __syncthreads();

    // ---- Phase 4: lanes 0..15 of wave 0: softmaxes + sinkhorn + fold post*pre
    if (tid < 16) {
        const int i = tid >> 2, j = tid & 3;

        float r0 = rawbuf[0], r1 = rawbuf[1], r2 = rawbuf[2], r3 = rawbuf[3];
        float mp = fmaxf(fmaxf(r0, r1), fmaxf(r2, r3));
        float sp = __expf(r0 - mp) + __expf(r1 - mp) + __expf(r2 - mp) + __expf(r3 - mp);
        float pre_j = __expf(rawbuf[j] - mp) / sp;

        float q0 = rawbuf[4], q1 = rawbuf[5], q2 = rawbuf[6], q3 = rawbuf[7];
        float mq = fmaxf(fmaxf(q0, q1), fmaxf(q2, q3));
        float sq = __expf(q0 - mq) + __expf(q1 - mq) + __expf(q2 - mq) + __expf(q3 - mq);
        float post_i = __expf(rawbuf[4 + i] - mq) / sq;

        // residual logits + (-2 off-diag, +2 diag) bias, exponentiate
        float w = __expf(rawbuf[8 + tid] + ((i == j) ? 2.0f : -2.0f));
#pragma unroll
        for (int it = 0; it < SINKHORN_ITERS; ++it) {
            // row normalize: sum over j (lanes differing in bits 0..1)
            float rs = w + __shfl_xor(w, 1);
            rs += __shfl_xor(rs, 2);
            w /= fmaxf(rs, EPSV);
            // col normalize: sum over i (lanes differing in bits 2..3)
            float cs = w + __shfl_xor(w, 4);
            cs += __shfl_xor(cs, 8);
            w /= fmaxf(cs, EPSV);
        }
        Mbuf[tid] = w + post_i * pre_j;   // fold post[i]*pre[j] into the 4x4 mix
    }
    __syncthreads();

    // ---- Phase 5: read x back from the LDS stash, apply the 4x4 mix, store.
    float M[16];
#pragma unroll
    for (int m = 0; m < 16; ++m) M[m] = Mbuf[m];

    f32x4 ya[4], yb[4];
#pragma unroll
    for (int w = 0; w < 4; ++w) {
        ya[w] = xs[w][tid];
        yb[w] = xs[4 + w][tid];
    }

#pragma unroll
    for (int i = 0; i < 4; ++i) {
        const float m0 = M[i * 4 + 0], m1 = M[i * 4 + 1];
        const float m2 = M[i * 4 + 2], m3 = M[i * 4 + 3];
        f32x4 oa = m0 * ya[0] + m1 * ya[1] + m2 * ya[2] + m3 * ya[3];
        f32x4 ob = m0 * yb[0] + m1 * yb[1] + m2 * yb[2] + m3 * yb[3];
        o4[i * 512 + tid]       = oa;
        o4[i * 512 + 256 + tid] = ob;
    }
}

extern "C" void kernel_launch(void* const* d_in, const int* in_sizes, int n_in,
                              void* d_out, int out_size, void* d_ws, size_t ws_size,
                              hipStream_t stream) {
    const float* x  = (const float*)d_in[0];
    const float* Wr = (const float*)d_in[1];
    const float* br = (const float*)d_in[2];
    float* out = (float*)d_out;

    const int tokens = in_sizes[0] / (4 * 2048);   // B*T = 8192
    mchc_fused<<<dim3(tokens), dim3(256), 0, stream>>>(x, Wr, br, out);
}